// Round 15
// baseline (411.443 us; speedup 1.0000x reference)
//
#include <hip/hip_runtime.h>

// 2-layer LSTM (H=50, B=4096, T=512, D_in=1) + FC(50->1), fused MFMA, round 15.
//
// = round-14 (13 waves x 1 tile, BT=16, 1 block/CU, 1 barrier/iter, gate-
// permuted pre-scaled rows, single-f16 weight product, single-f16 h state,
// merged-rcp cell) + three VALU trims:
//  1. x RIDES THE MFMA: K-slot 50 of the h1 B-fragment (a zero-weight dummy,
//     written with garbage by wave 12's q==2 lane) now carries x(t); the
//     A-fragments carry s_g*W_ih0 at k=50. L0's per-iter bias+x init
//     (4 FMA + LDS read, all 13 waves) collapses into the MFMA with the bias
//     vector as the DIRECT C operand (no acc-init movs). Same for L1 (cc1v).
//  2. Single-sided clamp in the tanh-exp (underflow side is NaN-safe).
//  3. xs read confined to wave 12 behind a wave-uniform branch.
// B-frag layout (r2-r14-verified): k -> ks=k>>5, lane=((k>>3)&3)*16+n, j=k&7;
// slot k=50 -> ks=1, q=2, j=2. L1 A-frag keeps k=50..63 zero (x must not
// leak into layer 1); h2 dummy slots k=114,115 stay zero-weighted.

#define TT 512
#define HH 50
#define BT 16
#define NTHR 832   // 13 waves
#define L2E 1.44269504f

typedef _Float16 half8 __attribute__((ext_vector_type(8)));
typedef float floatx4 __attribute__((ext_vector_type(4)));

static __device__ __forceinline__ float fexp2(float x) { return __builtin_amdgcn_exp2f(x); }
static __device__ __forceinline__ float frcp(float x)  { return __builtin_amdgcn_rcpf(x); }

// PRE-SCALED cell update (inputs are s_g*gate): 5 exp + 2 rcp.
// c' = R*[c*(1+Ei)(1+Eg) + (1-Eg)(1+Ef)], R = rcp((1+Ef)(1+Ei)(1+Eg));
// h = sig(o)*tanh(c'). Single-sided clamp: only the +arg (c very negative)
// side can make inf*0 NaN; exp2 underflow (c positive) is safe.
static __device__ __forceinline__ float cell_update(float gi, float gf, float gg,
                                                    float go, float& c) {
    float Ei = fexp2(gi);
    float Eg = fexp2(gg);
    float Ef = fexp2(gf);
    float p1 = (1.0f + Ei) * (1.0f + Eg);
    float fe = 1.0f + Ef;
    float R  = frcp(fe * p1);
    c = R * (c * p1 + (1.0f - Eg) * fe);
    float Eo = fexp2(go);
    float Ec = fexp2(fminf(c * (-2.0f * L2E), 40.0f));
    float Ro = frcp((1.0f + Eo) * (1.0f + Ec));
    return (1.0f - Ec) * Ro;
}

#define MFMA(a, b, c) __builtin_amdgcn_mfma_f32_16x16x32_f16((a), (b), (c), 0, 0, 0)

__global__ __launch_bounds__(NTHR, 4) void lstm_mfma(
    const float* __restrict__ x,
    const float* __restrict__ W_ih0, const float* __restrict__ W_hh0,
    const float* __restrict__ b_ih0, const float* __restrict__ b_hh0,
    const float* __restrict__ W_ih1, const float* __restrict__ W_hh1,
    const float* __restrict__ b_ih1, const float* __restrict__ b_hh1,
    const float* __restrict__ W_fc,  const float* __restrict__ b_fc,
    float* __restrict__ out)
{
    __shared__ __align__(16) _Float16 Hf[2][2048];   // [buf][(ks*64+lane)*8+j]
    __shared__ float xs[TT * BT];

    const int tid = threadIdx.x;
    const int ln  = tid & 63;
    const int wv  = tid >> 6;         // wave 0..12 == tile index (both layers)
    const int m   = ln & 15;          // batch col
    const int q   = ln >> 4;          // quad
    const int b0g = blockIdx.x * BT;

    // per-gate exp2 pre-scales: i,f,o -> -log2e ; g(cell) -> -2log2e
    const float GSC[4] = { -L2E, -L2E, -2.0f * L2E, -L2E };

    // ---------------- one-time init ----------------
    for (int i = tid; i < BT * TT; i += NTHR) {
        int b = i & 15, t = i >> 4;
        xs[t * BT + b] = x[(size_t)(b0g + b) * TT + t];
    }
    for (int i = tid; i < 2 * 2048; i += NTHR) ((_Float16*)Hf)[i] = (_Float16)0.f;

    // ---- A-fragments (gate-permuted rows), single f16, PRE-SCALED ----
    const int  uA   = 4 * wv + (m >> 2);
    const int  gA   = m & 3;
    const bool rokA = (uA < HH);
    const int  wrow = gA * HH + uA;
    const float sA  = GSC[gA];

    half8 a0[2];                      // layer-0: W_hh0 (k<50) + W_ih0 at k=50
    half8 a1[4];                      // layer-1: [W_ih1|pad|W_hh1|pad]
#pragma unroll
    for (int ks = 0; ks < 2; ++ks) {
        half8 h8;
#pragma unroll
        for (int j = 0; j < 8; ++j) {
            int k = ks * 32 + q * 8 + j;
            float w = 0.f;
            if (rokA) {
                if (k < HH)        w = W_hh0[wrow * HH + k];
                else if (k == 50)  w = W_ih0[wrow];     // x rides K-slot 50
            }
            h8[j] = (_Float16)(sA * w);
        }
        a0[ks] = h8;
    }
#pragma unroll
    for (int ks = 0; ks < 4; ++ks) {
        half8 h8;
#pragma unroll
        for (int j = 0; j < 8; ++j) {
            int k = ks * 32 + q * 8 + j;
            float w = 0.f;
            if (rokA) {
                if (k < HH)                      w = W_ih1[wrow * HH + k];
                else if (k >= 64 && k < 64 + HH) w = W_hh1[wrow * HH + (k - 64)];
            }
            h8[j] = (_Float16)(sA * w);
        }
        a1[ks] = h8;
    }

    // ---- C-lane constants (pre-scaled): unit uC = 4*wv + q, gate g = reg ----
    const int  uC = 4 * wv + q;       // 50 (wave12,q=2) = x-writer; 51 = dummy
    const bool vC = (uC < HH);
    floatx4 cc0v, cc1v;
    float bw0[4];                     // peel (t=0) only
#pragma unroll
    for (int g = 0; g < 4; ++g) {
        int rg = g * HH + (vC ? uC : 0);
        cc0v[g] = vC ? GSC[g] * (b_ih0[rg] + b_hh0[rg]) : 0.f;
        bw0[g]  = vC ? GSC[g] * W_ih0[rg] : 0.f;
        cc1v[g] = vC ? GSC[g] * (b_ih1[rg] + b_hh1[rg]) : 0.f;
    }
    const int kh = uC & 63;           // k slot this lane writes (50 = x slot)
    const int widx = ((kh >> 5) * 64 + ((kh >> 3) & 3) * 16 + m) * 8 + (kh & 7);
    float c1 = 0.f, c2 = 0.f;

    __syncthreads();

    // one iteration: snapshot buf P (compile-time), L0(t=ttv) if DO_L0,
    // L1(t=ttv-1), write h (or x(ttv+1) for the x-writer lane) -> buf P^1.
#define ITER(ttv, P, DO_L0)                                               \
    {                                                                     \
        half8 b0 = *(const half8*)&Hf[(P)][(0 * 64 + ln) * 8];            \
        half8 b1 = *(const half8*)&Hf[(P)][(1 * 64 + ln) * 8];            \
        half8 b2 = *(const half8*)&Hf[(P)][(2 * 64 + ln) * 8];            \
        half8 b3 = *(const half8*)&Hf[(P)][(3 * 64 + ln) * 8];            \
        if (DO_L0) {                                                      \
            floatx4 acc = MFMA(a0[0], b0, cc0v);                          \
            acc = MFMA(a0[1], b1, acc);                                   \
            float h = cell_update(acc[0], acc[1], acc[2], acc[3], c1);    \
            float wval = h;                                               \
            if (wv == 12) {                                               \
                int xn = (ttv) + 1; if (xn > TT - 1) xn = TT - 1;         \
                float xv = xs[xn * BT + m];                               \
                wval = (q == 2) ? xv : h;                                 \
            }                                                             \
            Hf[(P) ^ 1][widx] = (_Float16)wval;                           \
        }                                                                 \
        {                                                                 \
            floatx4 acc = MFMA(a1[0], b0, cc1v);                          \
            acc = MFMA(a1[1], b1, acc);                                   \
            acc = MFMA(a1[2], b2, acc);                                   \
            acc = MFMA(a1[3], b3, acc);                                   \
            float h = cell_update(acc[0], acc[1], acc[2], acc[3], c2);    \
            Hf[(P) ^ 1][widx + 1024] = (_Float16)h;                       \
        }                                                                 \
        __syncthreads();                                                  \
    }

    // ---- tt = 0 (p=0): h=0 -> explicit bias+x math, no MFMA; seed x(1) ----
    {
        const float xv0 = xs[m];      // x(0)
        float h = cell_update(cc0v[0] + bw0[0] * xv0, cc0v[1] + bw0[1] * xv0,
                              cc0v[2] + bw0[2] * xv0, cc0v[3] + bw0[3] * xv0, c1);
        float wval = h;
        if (wv == 12) {
            float x1 = xs[BT + m];    // x(1)
            wval = (q == 2) ? x1 : h;
        }
        Hf[1][widx] = (_Float16)wval;
        __syncthreads();
    }

    // ---- steady state: pairs (2k-1 [p=1], 2k [p=0]) for k = 1..255 ----
    for (int k = 1; k <= 255; ++k) {
        ITER(2 * k - 1, 1, true);
        ITER(2 * k,     0, true);
    }
    // ---- tail: tt = 511 (p=1, both), tt = 512 (p=0, L1 only) ----
    ITER(511, 1, true);
    ITER(512, 0, false);

    // ---------------- FC epilogue: h2(511) in buf 1, slots k = 64+u ----------------
    if (tid < BT) {
        float a = b_fc[0];
        for (int u = 0; u < HH; ++u) {
            int k = 64 + u;
            int idx = ((k >> 5) * 64 + ((k >> 3) & 3) * 16 + tid) * 8 + (k & 7);
            a = fmaf((float)Hf[1][idx], W_fc[u], a);
        }
        out[b0g + tid] = a;
    }
#undef ITER
}

extern "C" void kernel_launch(void* const* d_in, const int* in_sizes, int n_in,
                              void* d_out, int out_size, void* d_ws, size_t ws_size,
                              hipStream_t stream) {
    const float* x     = (const float*)d_in[0];
    const float* W_ih0 = (const float*)d_in[1];
    const float* W_hh0 = (const float*)d_in[2];
    const float* b_ih0 = (const float*)d_in[3];
    const float* b_hh0 = (const float*)d_in[4];
    const float* W_ih1 = (const float*)d_in[5];
    const float* W_hh1 = (const float*)d_in[6];
    const float* b_ih1 = (const float*)d_in[7];
    const float* b_hh1 = (const float*)d_in[8];
    const float* W_fc  = (const float*)d_in[9];
    const float* b_fc  = (const float*)d_in[10];
    float* out = (float*)d_out;

    dim3 grid(4096 / BT);   // 256 blocks = 1/CU
    dim3 block(NTHR);       // 13 waves
    lstm_mfma<<<grid, block, 0, stream>>>(x, W_ih0, W_hh0, b_ih0, b_hh0,
                                          W_ih1, W_hh1, b_ih1, b_hh1,
                                          W_fc, b_fc, out);
}